// Round 1
// 768.621 us; speedup vs baseline: 1.0208x; 1.0208x over previous
//
#include <hip/hip_runtime.h>
#include <math.h>

#define N_PROP 1024
#define DAPP   2048
#define DK     128

// ---------------------------------------------------------------------------
// Kernel 0: seed Q/K/V with their biases (ws is poisoned 0xAA before each call)
// ---------------------------------------------------------------------------
__global__ __launch_bounds__(256) void init_bias_kernel(
    const float* __restrict__ bQ, const float* __restrict__ bK,
    const float* __restrict__ bV,
    float* __restrict__ Q, float* __restrict__ K, float* __restrict__ V) {
  int i = blockIdx.x * 256 + threadIdx.x;
  if (i < N_PROP * DK) {
    int c = i & (DK - 1);
    Q[i] = bQ[c];
    K[i] = bK[c];
    V[i] = bV[c];
  }
}

// ---------------------------------------------------------------------------
// Kernel 1: fused QKV projection.  C = X (1024x2048) @ W^T (2048x128) per proj.
// 64x64 output tile, 4x4 register blocking, split-k=4 via atomicAdd.
// grid = (6 col-tiles [3 proj x 2], 16 row-tiles, 4 k-splits), block = 256.
// ---------------------------------------------------------------------------
#define BM 64
#define BN 64
#define KC 32
#define KSPLIT_CHUNK 512

__global__ __launch_bounds__(256) void proj_kernel(
    const float* __restrict__ X,
    const float* __restrict__ WQ, const float* __restrict__ WK,
    const float* __restrict__ WV,
    float* __restrict__ Q, float* __restrict__ K, float* __restrict__ V) {
  __shared__ __attribute__((aligned(16))) float As[KC][BM + 4];
  __shared__ __attribute__((aligned(16))) float Bs[KC][BN + 4];

  const int nt = blockIdx.x;        // 0..5 : which 64-col slab of the 384 cols
  const int mt = blockIdx.y;        // 0..15
  const int kz = blockIdx.z;        // 0..3
  const int row0 = mt * BM;
  const int proj = nt >> 1;         // 0=Q 1=K 2=V
  const int col0 = (nt & 1) * 64;   // col offset inside the 128-wide proj

  const float* __restrict__ W = (proj == 0) ? WQ : ((proj == 1) ? WK : WV);
  float* __restrict__ O = (proj == 0) ? Q : ((proj == 1) ? K : V);

  const int t  = threadIdx.x;
  const int tx = t & 15, ty = t >> 4;   // 16x16 thread grid, 4x4 each
  const int kk = t & 31, mm = t >> 5;   // loader coords

  float acc[4][4] = {};

  const int k0base = kz * KSPLIT_CHUNK;
  for (int k0 = k0base; k0 < k0base + KSPLIT_CHUNK; k0 += KC) {
    __syncthreads();
#pragma unroll
    for (int r = 0; r < 8; ++r) {
      As[kk][mm + r * 8] = X[(size_t)(row0 + mm + r * 8) * DAPP + k0 + kk];
      Bs[kk][mm + r * 8] = W[(size_t)(col0 + mm + r * 8) * DAPP + k0 + kk];
    }
    __syncthreads();
#pragma unroll
    for (int k = 0; k < KC; ++k) {
      float4 a = *(const float4*)&As[k][ty * 4];
      float4 b = *(const float4*)&Bs[k][tx * 4];
      acc[0][0] += a.x * b.x; acc[0][1] += a.x * b.y; acc[0][2] += a.x * b.z; acc[0][3] += a.x * b.w;
      acc[1][0] += a.y * b.x; acc[1][1] += a.y * b.y; acc[1][2] += a.y * b.z; acc[1][3] += a.y * b.w;
      acc[2][0] += a.z * b.x; acc[2][1] += a.z * b.y; acc[2][2] += a.z * b.z; acc[2][3] += a.z * b.w;
      acc[3][0] += a.w * b.x; acc[3][1] += a.w * b.y; acc[3][2] += a.w * b.z; acc[3][3] += a.w * b.w;
    }
  }

#pragma unroll
  for (int i = 0; i < 4; ++i)
#pragma unroll
    for (int j = 0; j < 4; ++j)
      atomicAdd(&O[(size_t)(row0 + ty * 4 + i) * DK + col0 + tx * 4 + j],
                acc[i][j]);
}

// ---------------------------------------------------------------------------
// Kernel 2: S = (Q @ K^T) / sqrt(128).  1024x1024 output, k=128.
// grid = (16, 16), block = 256.
// ---------------------------------------------------------------------------
__global__ __launch_bounds__(256) void score_kernel(
    const float* __restrict__ Q, const float* __restrict__ Kmat,
    float* __restrict__ S) {
  __shared__ __attribute__((aligned(16))) float As[KC][BM + 4];
  __shared__ __attribute__((aligned(16))) float Bs[KC][BN + 4];

  const int col0 = blockIdx.x * BN;
  const int row0 = blockIdx.y * BM;
  const int t  = threadIdx.x;
  const int tx = t & 15, ty = t >> 4;
  const int kk = t & 31, mm = t >> 5;

  float acc[4][4] = {};

  for (int k0 = 0; k0 < DK; k0 += KC) {
    __syncthreads();
#pragma unroll
    for (int r = 0; r < 8; ++r) {
      As[kk][mm + r * 8] = Q[(size_t)(row0 + mm + r * 8) * DK + k0 + kk];
      Bs[kk][mm + r * 8] = Kmat[(size_t)(col0 + mm + r * 8) * DK + k0 + kk];
    }
    __syncthreads();
#pragma unroll
    for (int k = 0; k < KC; ++k) {
      float4 a = *(const float4*)&As[k][ty * 4];
      float4 b = *(const float4*)&Bs[k][tx * 4];
      acc[0][0] += a.x * b.x; acc[0][1] += a.x * b.y; acc[0][2] += a.x * b.z; acc[0][3] += a.x * b.w;
      acc[1][0] += a.y * b.x; acc[1][1] += a.y * b.y; acc[1][2] += a.y * b.z; acc[1][3] += a.y * b.w;
      acc[2][0] += a.z * b.x; acc[2][1] += a.z * b.y; acc[2][2] += a.z * b.z; acc[2][3] += a.z * b.w;
      acc[3][0] += a.w * b.x; acc[3][1] += a.w * b.y; acc[3][2] += a.w * b.z; acc[3][3] += a.w * b.w;
    }
  }

  const float scale = 0.08838834764831845f; // 1/sqrt(128)
#pragma unroll
  for (int i = 0; i < 4; ++i)
#pragma unroll
    for (int j = 0; j < 4; ++j)
      S[(size_t)(row0 + ty * 4 + i) * N_PROP + col0 + tx * 4 + j] =
          acc[i][j] * scale;
}

// ---------------------------------------------------------------------------
// Kernel 3 (FUSED): per-row m — stream pos[m] (512 KB contiguous) computing
// g[n] = relu(pos[m,n,:].wg + bg) directly into LDS (G never materialized),
// then softmax(S[m,:] + g) and P@V, all in one block.
//
// Phase A keeps the proven half-wave pattern: 8 half-waves x 4 rows/iter,
// 4 independent coalesced 512B loads in flight, shuffle-tree reduce (same
// reduction order as the old bias_kernel -> bit-identical numerics).
// grid = 1024 blocks (1 row each) x 256 thr = 4 blocks/CU, 16 waves/CU.
// LDS: 4KB p-row + 4KB accs + 16B wred = 8.2 KB.
// ---------------------------------------------------------------------------
__global__ __launch_bounds__(256) void fused_gsm_pv_kernel(
    const float* __restrict__ pos, const float* __restrict__ S,
    const float* __restrict__ V, const float* __restrict__ wg,
    const float* __restrict__ bg, float* __restrict__ out) {
  __shared__ __attribute__((aligned(16))) float p[N_PROP];   // g row, then P row
  __shared__ __attribute__((aligned(16))) float4 accs[256];
  __shared__ float wred[4];

  const int m = blockIdx.x;
  const int t = threadIdx.x;
  const int l  = t & 31;     // lane in half-wave
  const int hw = t >> 5;     // half-wave id 0..7

  const float4 w4 = *(const float4*)&wg[l * 4];   // 32 lanes cover 128 dims
  const float bG = bg[0];

  // ---- Phase A: geometric-bias row into LDS ----
  {
    const float* __restrict__ pr =
        pos + (size_t)m * N_PROP * DK + (size_t)(hw * 4) * DK + (l << 2);
#pragma unroll 4
    for (int it = 0; it < 32; ++it, pr += 32 * DK) {
      const float4 p0 = *(const float4*)(pr);
      const float4 p1 = *(const float4*)(pr + DK);
      const float4 p2 = *(const float4*)(pr + 2 * DK);
      const float4 p3 = *(const float4*)(pr + 3 * DK);

      float d0 = fmaf(p0.x, w4.x, fmaf(p0.y, w4.y, fmaf(p0.z, w4.z, p0.w * w4.w)));
      float d1 = fmaf(p1.x, w4.x, fmaf(p1.y, w4.y, fmaf(p1.z, w4.z, p1.w * w4.w)));
      float d2 = fmaf(p2.x, w4.x, fmaf(p2.y, w4.y, fmaf(p2.z, w4.z, p2.w * w4.w)));
      float d3 = fmaf(p3.x, w4.x, fmaf(p3.y, w4.y, fmaf(p3.z, w4.z, p3.w * w4.w)));

#pragma unroll
      for (int off = 16; off; off >>= 1) {   // stays within the 32-lane half
        d0 += __shfl_xor(d0, off, 64);
        d1 += __shfl_xor(d1, off, 64);
        d2 += __shfl_xor(d2, off, 64);
        d3 += __shfl_xor(d3, off, 64);
      }
      if (l == 0) {
        float4 g;
        g.x = fmaxf(d0 + bG, 0.0f);
        g.y = fmaxf(d1 + bG, 0.0f);
        g.z = fmaxf(d2 + bG, 0.0f);
        g.w = fmaxf(d3 + bG, 0.0f);
        *(float4*)&p[hw * 4 + it * 32] = g;
      }
    }
  }
  __syncthreads();   // publish g row

  // ---- Phase B: logits = S + g, row softmax ----
  const float4 sr = ((const float4*)(S + (size_t)m * N_PROP))[t];
  const float4 gr = ((const float4*)p)[t];
  const float4 s4 = make_float4(sr.x + gr.x, sr.y + gr.y, sr.z + gr.z, sr.w + gr.w);

  float mx = fmaxf(fmaxf(s4.x, s4.y), fmaxf(s4.z, s4.w));
#pragma unroll
  for (int off = 32; off; off >>= 1) mx = fmaxf(mx, __shfl_xor(mx, off, 64));
  if ((t & 63) == 0) wred[t >> 6] = mx;
  __syncthreads();
  mx = fmaxf(fmaxf(wred[0], wred[1]), fmaxf(wred[2], wred[3]));

  const float e0 = __expf(s4.x - mx), e1 = __expf(s4.y - mx);
  const float e2 = __expf(s4.z - mx), e3 = __expf(s4.w - mx);
  float sum = e0 + e1 + e2 + e3;
#pragma unroll
  for (int off = 32; off; off >>= 1) sum += __shfl_xor(sum, off, 64);
  __syncthreads();               // all wred (mx) reads done before overwrite
  ((float4*)p)[t] = make_float4(e0, e1, e2, e3);  // own slot: no cross-thread hazard
  if ((t & 63) == 0) wred[t >> 6] = sum;
  __syncthreads();               // publishes p[] and wred
  sum = wred[0] + wred[1] + wred[2] + wred[3];
  const float inv = 1.0f / sum;

  // ---- Phase C: P @ V : 8 n-groups x 32 lanes x float4 cols, unroll x4 ----
  const int dq = (t & 31) << 2;  // col offset 0..124 (x4)
  const int ng = t >> 5;         // 0..7
  float4 acc = make_float4(0.f, 0.f, 0.f, 0.f);
  for (int n = ng; n < N_PROP; n += 32) {
    const float pw0 = p[n];
    const float pw1 = p[n + 8];
    const float pw2 = p[n + 16];
    const float pw3 = p[n + 24];
    const float4 v0 = *(const float4*)&V[(size_t)n * DK + dq];
    const float4 v1 = *(const float4*)&V[(size_t)(n + 8) * DK + dq];
    const float4 v2 = *(const float4*)&V[(size_t)(n + 16) * DK + dq];
    const float4 v3 = *(const float4*)&V[(size_t)(n + 24) * DK + dq];
    acc.x += pw0 * v0.x + pw1 * v1.x + pw2 * v2.x + pw3 * v3.x;
    acc.y += pw0 * v0.y + pw1 * v1.y + pw2 * v2.y + pw3 * v3.y;
    acc.z += pw0 * v0.z + pw1 * v1.z + pw2 * v2.z + pw3 * v3.z;
    acc.w += pw0 * v0.w + pw1 * v1.w + pw2 * v2.w + pw3 * v3.w;
  }
  accs[t] = acc;
  __syncthreads();
  if (t < 32) {
    float4 r = accs[t];
#pragma unroll
    for (int g = 1; g < 8; ++g) {
      const float4 o = accs[t + g * 32];
      r.x += o.x; r.y += o.y; r.z += o.z; r.w += o.w;
    }
    r.x *= inv; r.y *= inv; r.z *= inv; r.w *= inv;
    *(float4*)&out[(size_t)m * DK + (t << 2)] = r;
  }
}

// ---------------------------------------------------------------------------
extern "C" void kernel_launch(void* const* d_in, const int* in_sizes, int n_in,
                              void* d_out, int out_size, void* d_ws,
                              size_t ws_size, hipStream_t stream) {
  const float* app = (const float*)d_in[0];   // (1024, 2048)
  const float* pos = (const float*)d_in[1];   // (1024, 1024, 128)
  const float* WQw = (const float*)d_in[2];
  const float* WQb = (const float*)d_in[3];
  const float* WKw = (const float*)d_in[4];
  const float* WKb = (const float*)d_in[5];
  const float* WVw = (const float*)d_in[6];
  const float* WVb = (const float*)d_in[7];
  const float* WGw = (const float*)d_in[8];
  const float* WGb = (const float*)d_in[9];
  float* out = (float*)d_out;

  float* ws = (float*)d_ws;
  float* Q = ws;                         // 1024*128
  float* K = ws + 131072;                // 1024*128
  float* V = ws + 262144;                // 1024*128
  float* S = ws + 393216;                // 1024*1024
  // G eliminated: computed in-LDS inside the fused kernel.

  init_bias_kernel<<<dim3(512), dim3(256), 0, stream>>>(WQb, WKb, WVb, Q, K, V);

  proj_kernel<<<dim3(6, 16, 4), dim3(256), 0, stream>>>(app, WQw, WKw, WVw,
                                                        Q, K, V);

  score_kernel<<<dim3(16, 16), dim3(256), 0, stream>>>(Q, K, S);

  fused_gsm_pv_kernel<<<dim3(1024), dim3(256), 0, stream>>>(pos, S, V,
                                                            WGw, WGb, out);
}

// Round 2
// 764.878 us; speedup vs baseline: 1.0258x; 1.0049x over previous
//
#include <hip/hip_runtime.h>
#include <math.h>

#define N_PROP 1024
#define DAPP   2048
#define DK     128

// ---------------------------------------------------------------------------
// Kernel 0: seed Q/K/V with their biases (ws is poisoned 0xAA before each call)
// ---------------------------------------------------------------------------
__global__ __launch_bounds__(256) void init_bias_kernel(
    const float* __restrict__ bQ, const float* __restrict__ bK,
    const float* __restrict__ bV,
    float* __restrict__ Q, float* __restrict__ K, float* __restrict__ V) {
  int i = blockIdx.x * 256 + threadIdx.x;
  if (i < N_PROP * DK) {
    int c = i & (DK - 1);
    Q[i] = bQ[c];
    K[i] = bK[c];
    V[i] = bV[c];
  }
}

// ---------------------------------------------------------------------------
// Kernel 1: fused QKV projection.  C = X (1024x2048) @ W^T (2048x128) per proj.
// 64x64 output tile, 4x4 register blocking, split-k=4 via atomicAdd.
// grid = (6 col-tiles [3 proj x 2], 16 row-tiles, 4 k-splits), block = 256.
// ---------------------------------------------------------------------------
#define BM 64
#define BN 64
#define KC 32
#define KSPLIT_CHUNK 512

__global__ __launch_bounds__(256) void proj_kernel(
    const float* __restrict__ X,
    const float* __restrict__ WQ, const float* __restrict__ WK,
    const float* __restrict__ WV,
    float* __restrict__ Q, float* __restrict__ K, float* __restrict__ V) {
  __shared__ __attribute__((aligned(16))) float As[KC][BM + 4];
  __shared__ __attribute__((aligned(16))) float Bs[KC][BN + 4];

  const int nt = blockIdx.x;        // 0..5 : which 64-col slab of the 384 cols
  const int mt = blockIdx.y;        // 0..15
  const int kz = blockIdx.z;        // 0..3
  const int row0 = mt * BM;
  const int proj = nt >> 1;         // 0=Q 1=K 2=V
  const int col0 = (nt & 1) * 64;   // col offset inside the 128-wide proj

  const float* __restrict__ W = (proj == 0) ? WQ : ((proj == 1) ? WK : WV);
  float* __restrict__ O = (proj == 0) ? Q : ((proj == 1) ? K : V);

  const int t  = threadIdx.x;
  const int tx = t & 15, ty = t >> 4;   // 16x16 thread grid, 4x4 each
  const int kk = t & 31, mm = t >> 5;   // loader coords

  float acc[4][4] = {};

  const int k0base = kz * KSPLIT_CHUNK;
  for (int k0 = k0base; k0 < k0base + KSPLIT_CHUNK; k0 += KC) {
    __syncthreads();
#pragma unroll
    for (int r = 0; r < 8; ++r) {
      As[kk][mm + r * 8] = X[(size_t)(row0 + mm + r * 8) * DAPP + k0 + kk];
      Bs[kk][mm + r * 8] = W[(size_t)(col0 + mm + r * 8) * DAPP + k0 + kk];
    }
    __syncthreads();
#pragma unroll
    for (int k = 0; k < KC; ++k) {
      float4 a = *(const float4*)&As[k][ty * 4];
      float4 b = *(const float4*)&Bs[k][tx * 4];
      acc[0][0] += a.x * b.x; acc[0][1] += a.x * b.y; acc[0][2] += a.x * b.z; acc[0][3] += a.x * b.w;
      acc[1][0] += a.y * b.x; acc[1][1] += a.y * b.y; acc[1][2] += a.y * b.z; acc[1][3] += a.y * b.w;
      acc[2][0] += a.z * b.x; acc[2][1] += a.z * b.y; acc[2][2] += a.z * b.z; acc[2][3] += a.z * b.w;
      acc[3][0] += a.w * b.x; acc[3][1] += a.w * b.y; acc[3][2] += a.w * b.z; acc[3][3] += a.w * b.w;
    }
  }

#pragma unroll
  for (int i = 0; i < 4; ++i)
#pragma unroll
    for (int j = 0; j < 4; ++j)
      atomicAdd(&O[(size_t)(row0 + ty * 4 + i) * DK + col0 + tx * 4 + j],
                acc[i][j]);
}

// ---------------------------------------------------------------------------
// Kernel 2 (MEGA): per-row m — Phase A streams pos[m] (512 KB, HBM) AND K
// (512 KB, L2-resident) together: for each proposal n the half-wave computes
//   g[n] = relu(pos[m,n,:].wg + bg)     (HBM stream, dot with wg)
//   s[n] = (q_m . K[n,:]) / sqrt(128)   (L2 stream, dot with q_m)
// through the same float4-load + 5-step shuffle-tree reduce, writing the
// combined logit s+g straight into LDS.  The score kernel's L2/VALU work thus
// hides under the HBM stream, and S is never materialized.
// Then row softmax + P@V as before (orders unchanged -> same numerics there).
// grid = 1024 blocks (1 row each) x 256 thr = 4 blocks/CU, 16 waves/CU.
// LDS: 4KB logit/p row + 4KB accs + 16B wred = 8.2 KB.
// ---------------------------------------------------------------------------
__global__ __launch_bounds__(256) void mega_row_kernel(
    const float* __restrict__ pos, const float* __restrict__ Q,
    const float* __restrict__ Kmat, const float* __restrict__ V,
    const float* __restrict__ wg, const float* __restrict__ bg,
    float* __restrict__ out) {
  __shared__ __attribute__((aligned(16))) float p[N_PROP];   // logits, then P
  __shared__ __attribute__((aligned(16))) float4 accs[256];
  __shared__ float wred[4];

  const int m = blockIdx.x;
  const int t = threadIdx.x;
  const int l  = t & 31;     // lane in half-wave
  const int hw = t >> 5;     // half-wave id 0..7

  const float4 w4 = *(const float4*)&wg[l * 4];          // 32 lanes cover D_G
  const float4 q4 = *(const float4*)&Q[(size_t)m * DK + l * 4]; // q_m slice
  const float bG = bg[0];
  const float scale = 0.08838834764831845f;              // 1/sqrt(128)

  // ---- Phase A: logits = s + g directly into LDS ----
  {
    const float* __restrict__ pr =
        pos + (size_t)m * N_PROP * DK + (size_t)(hw * 4) * DK + (l << 2);
    const float* __restrict__ kr = Kmat + (size_t)(hw * 4) * DK + (l << 2);
#pragma unroll 2
    for (int it = 0; it < 32; ++it, pr += 32 * DK, kr += 32 * DK) {
      const float4 p0 = *(const float4*)(pr);
      const float4 p1 = *(const float4*)(pr + DK);
      const float4 p2 = *(const float4*)(pr + 2 * DK);
      const float4 p3 = *(const float4*)(pr + 3 * DK);
      const float4 k0 = *(const float4*)(kr);
      const float4 k1 = *(const float4*)(kr + DK);
      const float4 k2 = *(const float4*)(kr + 2 * DK);
      const float4 k3 = *(const float4*)(kr + 3 * DK);

      float g0 = fmaf(p0.x, w4.x, fmaf(p0.y, w4.y, fmaf(p0.z, w4.z, p0.w * w4.w)));
      float g1 = fmaf(p1.x, w4.x, fmaf(p1.y, w4.y, fmaf(p1.z, w4.z, p1.w * w4.w)));
      float g2 = fmaf(p2.x, w4.x, fmaf(p2.y, w4.y, fmaf(p2.z, w4.z, p2.w * w4.w)));
      float g3 = fmaf(p3.x, w4.x, fmaf(p3.y, w4.y, fmaf(p3.z, w4.z, p3.w * w4.w)));
      float s0 = fmaf(k0.x, q4.x, fmaf(k0.y, q4.y, fmaf(k0.z, q4.z, k0.w * q4.w)));
      float s1 = fmaf(k1.x, q4.x, fmaf(k1.y, q4.y, fmaf(k1.z, q4.z, k1.w * q4.w)));
      float s2 = fmaf(k2.x, q4.x, fmaf(k2.y, q4.y, fmaf(k2.z, q4.z, k2.w * q4.w)));
      float s3 = fmaf(k3.x, q4.x, fmaf(k3.y, q4.y, fmaf(k3.z, q4.z, k3.w * q4.w)));

#pragma unroll
      for (int off = 16; off; off >>= 1) {   // stays within the 32-lane half
        g0 += __shfl_xor(g0, off, 64);
        g1 += __shfl_xor(g1, off, 64);
        g2 += __shfl_xor(g2, off, 64);
        g3 += __shfl_xor(g3, off, 64);
        s0 += __shfl_xor(s0, off, 64);
        s1 += __shfl_xor(s1, off, 64);
        s2 += __shfl_xor(s2, off, 64);
        s3 += __shfl_xor(s3, off, 64);
      }
      if (l == 0) {
        float4 lg;
        lg.x = fmaf(s0, scale, fmaxf(g0 + bG, 0.0f));
        lg.y = fmaf(s1, scale, fmaxf(g1 + bG, 0.0f));
        lg.z = fmaf(s2, scale, fmaxf(g2 + bG, 0.0f));
        lg.w = fmaf(s3, scale, fmaxf(g3 + bG, 0.0f));
        *(float4*)&p[hw * 4 + it * 32] = lg;
      }
    }
  }
  __syncthreads();   // publish logit row

  // ---- Phase B: row softmax over p[] ----
  const float4 s4 = ((const float4*)p)[t];   // own logits (read before overwrite)

  float mx = fmaxf(fmaxf(s4.x, s4.y), fmaxf(s4.z, s4.w));
#pragma unroll
  for (int off = 32; off; off >>= 1) mx = fmaxf(mx, __shfl_xor(mx, off, 64));
  if ((t & 63) == 0) wred[t >> 6] = mx;
  __syncthreads();
  mx = fmaxf(fmaxf(wred[0], wred[1]), fmaxf(wred[2], wred[3]));

  const float e0 = __expf(s4.x - mx), e1 = __expf(s4.y - mx);
  const float e2 = __expf(s4.z - mx), e3 = __expf(s4.w - mx);
  float sum = e0 + e1 + e2 + e3;
#pragma unroll
  for (int off = 32; off; off >>= 1) sum += __shfl_xor(sum, off, 64);
  __syncthreads();               // all wred (mx) reads done before overwrite
  ((float4*)p)[t] = make_float4(e0, e1, e2, e3);  // own slot: no hazard
  if ((t & 63) == 0) wred[t >> 6] = sum;
  __syncthreads();               // publishes p[] and wred
  sum = wred[0] + wred[1] + wred[2] + wred[3];
  const float inv = 1.0f / sum;

  // ---- Phase C: P @ V : 8 n-groups x 32 lanes x float4 cols, unroll x4 ----
  const int dq = (t & 31) << 2;  // col offset 0..124 (x4)
  const int ng = t >> 5;         // 0..7
  float4 acc = make_float4(0.f, 0.f, 0.f, 0.f);
  for (int n = ng; n < N_PROP; n += 32) {
    const float pw0 = p[n];
    const float pw1 = p[n + 8];
    const float pw2 = p[n + 16];
    const float pw3 = p[n + 24];
    const float4 v0 = *(const float4*)&V[(size_t)n * DK + dq];
    const float4 v1 = *(const float4*)&V[(size_t)(n + 8) * DK + dq];
    const float4 v2 = *(const float4*)&V[(size_t)(n + 16) * DK + dq];
    const float4 v3 = *(const float4*)&V[(size_t)(n + 24) * DK + dq];
    acc.x += pw0 * v0.x + pw1 * v1.x + pw2 * v2.x + pw3 * v3.x;
    acc.y += pw0 * v0.y + pw1 * v1.y + pw2 * v2.y + pw3 * v3.y;
    acc.z += pw0 * v0.z + pw1 * v1.z + pw2 * v2.z + pw3 * v3.z;
    acc.w += pw0 * v0.w + pw1 * v1.w + pw2 * v2.w + pw3 * v3.w;
  }
  accs[t] = acc;
  __syncthreads();
  if (t < 32) {
    float4 r = accs[t];
#pragma unroll
    for (int g = 1; g < 8; ++g) {
      const float4 o = accs[t + g * 32];
      r.x += o.x; r.y += o.y; r.z += o.z; r.w += o.w;
    }
    r.x *= inv; r.y *= inv; r.z *= inv; r.w *= inv;
    *(float4*)&out[(size_t)m * DK + (t << 2)] = r;
  }
}

// ---------------------------------------------------------------------------
extern "C" void kernel_launch(void* const* d_in, const int* in_sizes, int n_in,
                              void* d_out, int out_size, void* d_ws,
                              size_t ws_size, hipStream_t stream) {
  const float* app = (const float*)d_in[0];   // (1024, 2048)
  const float* pos = (const float*)d_in[1];   // (1024, 1024, 128)
  const float* WQw = (const float*)d_in[2];
  const float* WQb = (const float*)d_in[3];
  const float* WKw = (const float*)d_in[4];
  const float* WKb = (const float*)d_in[5];
  const float* WVw = (const float*)d_in[6];
  const float* WVb = (const float*)d_in[7];
  const float* WGw = (const float*)d_in[8];
  const float* WGb = (const float*)d_in[9];
  float* out = (float*)d_out;

  float* ws = (float*)d_ws;
  float* Q = ws;                         // 1024*128
  float* K = ws + 131072;                // 1024*128
  float* V = ws + 262144;                // 1024*128
  // S and G eliminated: computed in-LDS inside the mega kernel.

  init_bias_kernel<<<dim3(512), dim3(256), 0, stream>>>(WQb, WKb, WVb, Q, K, V);

  proj_kernel<<<dim3(6, 16, 4), dim3(256), 0, stream>>>(app, WQw, WKw, WVw,
                                                        Q, K, V);

  mega_row_kernel<<<dim3(1024), dim3(256), 0, stream>>>(pos, Q, K, V,
                                                        WGw, WGb, out);
}